// Round 12
// baseline (167.692 us; speedup 1.0000x reference)
//
#include <hip/hip_runtime.h>

#define F_DIM 128
#define TE_DIM 32
#define DD 160
#define NB 4096
#define KK 64
#define ROWS 4
#define LD 164         // padded fp32 LDS row stride
#define XH_STRIDE 168  // staged fp16 row stride (84 dwords; 16B-aligned rows)
#define KT 8           // k-tile size per half-wave (4 tiles per half)

// ws layout (float offsets)
#define WS_M   0          // [160][160]  (Wk^T Wq) / sqrt(160)
#define WS_V2  25600      // [160][160]  out_w @ Wv
#define WS_C   51200      // [160]       (Wk^T bq) / sqrt(160)
#define WS_U   51360      // [160]       (Wq^T bk) / sqrt(160)
#define WS_B2  51520      // [160]       out_w @ bv + out_b
#define WS_S0  51680      // [1]         (bq . bk) / sqrt(160)
#define WS_TE  51684      // [10000][32] cos(t*te_w[d]+te_b[d])
#define TAB_T  10000
#define TAB_N  (TAB_T * TE_DIM)
#define TAB_BLOCKS 250
#define SETUP_BASE (2 * DD + 3)

__device__ __forceinline__ float dot4acc(const float4 w, const float4 v, float a) {
    a = fmaf(w.x, v.x, a);
    a = fmaf(w.y, v.y, a);
    a = fmaf(w.z, v.z, a);
    a = fmaf(w.w, v.w, a);
    return a;
}

__device__ __forceinline__ float wave_max(float v) {
    #pragma unroll
    for (int off = 32; off > 0; off >>= 1) v = fmaxf(v, __shfl_xor(v, off, 64));
    return v;
}
__device__ __forceinline__ float wave_sum(float v) {
    #pragma unroll
    for (int off = 32; off > 0; off >>= 1) v += __shfl_xor(v, off, 64);
    return v;
}

// 512-thread block-cooperative GEMV (R5-verified): r = tid&3, dl = tid>>2.
// Lanes 4t..4t+3 share weight addresses -> 4:1 dedup in the coalescer.
__device__ __forceinline__ void gemv512(
    const float* __restrict__ W, const float* __restrict__ bias,
    const float (*vin)[LD], float (*vout)[LD], int tid)
{
    const int r  = tid & 3;
    const int dl = tid >> 2;  // 0..127
    const float4* v4 = (const float4*)vin[r];
    const float4* w0 = (const float4*)(W + (long)dl * DD);
    float a0 = bias[dl];
    if (dl < 32) {
        const float4* w1 = (const float4*)(W + (long)(dl + 128) * DD);
        float a1 = bias[dl + 128];
        #pragma unroll 8
        for (int f = 0; f < 40; ++f) {
            const float4 v = v4[f];
            a0 = dot4acc(w0[f], v, a0);
            a1 = dot4acc(w1[f], v, a1);
        }
        vout[r][dl]       = a0;
        vout[r][dl + 128] = a1;
    } else {
        #pragma unroll 8
        for (int f = 0; f < 40; ++f) {
            const float4 v = v4[f];
            a0 = dot4acc(w0[f], v, a0);
        }
        vout[r][dl] = a0;
    }
}

// Same, input = sum of two k-half partials (R5-verified shape).
__device__ __forceinline__ void gemv512_2(
    const float* __restrict__ W, const float* __restrict__ bias,
    const float (*vin)[2][LD], float (*vout)[LD], int tid)
{
    const int r  = tid & 3;
    const int dl = tid >> 2;
    const float4* va = (const float4*)vin[r][0];
    const float4* vb = (const float4*)vin[r][1];
    const float4* w0 = (const float4*)(W + (long)dl * DD);
    float a0 = bias[dl];
    if (dl < 32) {
        const float4* w1 = (const float4*)(W + (long)(dl + 128) * DD);
        float a1 = bias[dl + 128];
        #pragma unroll 8
        for (int f = 0; f < 40; ++f) {
            const float4 A = va[f], B = vb[f];
            float4 v; v.x = A.x + B.x; v.y = A.y + B.y; v.z = A.z + B.z; v.w = A.w + B.w;
            a0 = dot4acc(w0[f], v, a0);
            a1 = dot4acc(w1[f], v, a1);
        }
        vout[r][dl]       = a0;
        vout[r][dl + 128] = a1;
    } else {
        #pragma unroll 8
        for (int f = 0; f < 40; ++f) {
            const float4 A = va[f], B = vb[f];
            float4 v; v.x = A.x + B.x; v.y = A.y + B.y; v.z = A.z + B.z; v.w = A.w + B.w;
            a0 = dot4acc(w0[f], v, a0);
        }
        vout[r][dl] = a0;
    }
}

// ---------------- setup: fold weight matrices + te table -------------------
__global__ __launch_bounds__(256)
void setup_kernel(const float* __restrict__ ipw, const float* __restrict__ ipb,
                  const float* __restrict__ ow,  const float* __restrict__ ob,
                  const float* __restrict__ te_w, const float* __restrict__ te_b,
                  float* __restrict__ ws)
{
    const int blk = blockIdx.x;
    const int t   = threadIdx.x;
    const float inv = 0.07905694150420949f;  // 1/sqrt(160)

    __shared__ float s_vec[DD];

    if (blk >= SETUP_BASE) {
        const int g0 = (blk - SETUP_BASE) * 256 + t;
        #pragma unroll
        for (int it = 0; it < 5; ++it) {
            const int g = g0 + it * (TAB_BLOCKS * 256);
            const int tt = g >> 5, d = g & 31;
            ws[WS_TE + g] = cosf(fmaf((float)tt, te_w[d], te_b[d]));
        }
        return;
    }

    if (blk < DD) {
        const float* wk = ipw + DD * DD;
        if (t < DD) s_vec[t] = wk[(long)t * DD + blk];
        __syncthreads();
        if (t < DD) {
            float a0 = 0.f, a1 = 0.f, a2 = 0.f, a3 = 0.f;
            #pragma unroll 4
            for (int d = 0; d < DD; d += 4) {
                a0 = fmaf(s_vec[d],     ipw[(long)d * DD + t],       a0);
                a1 = fmaf(s_vec[d + 1], ipw[(long)(d + 1) * DD + t], a1);
                a2 = fmaf(s_vec[d + 2], ipw[(long)(d + 2) * DD + t], a2);
                a3 = fmaf(s_vec[d + 3], ipw[(long)(d + 3) * DD + t], a3);
            }
            ws[WS_M + blk * DD + t] = (a0 + a1 + a2 + a3) * inv;
        }
    } else if (blk < 2 * DD) {
        const int i = blk - DD;
        const float* wv = ipw + 2 * DD * DD;
        if (t < DD) s_vec[t] = ow[(long)i * DD + t];
        __syncthreads();
        if (t < DD) {
            float a0 = 0.f, a1 = 0.f, a2 = 0.f, a3 = 0.f;
            #pragma unroll 4
            for (int d = 0; d < DD; d += 4) {
                a0 = fmaf(s_vec[d],     wv[(long)d * DD + t],       a0);
                a1 = fmaf(s_vec[d + 1], wv[(long)(d + 1) * DD + t], a1);
                a2 = fmaf(s_vec[d + 2], wv[(long)(d + 2) * DD + t], a2);
                a3 = fmaf(s_vec[d + 3], wv[(long)(d + 3) * DD + t], a3);
            }
            ws[WS_V2 + i * DD + t] = a0 + a1 + a2 + a3;
        }
    } else if (blk == 2 * DD) {
        const float* wk = ipw + DD * DD;
        if (t < DD) s_vec[t] = ipb[t];
        __syncthreads();
        if (t < DD) {
            float a0 = 0.f, a1 = 0.f, a2 = 0.f, a3 = 0.f;
            #pragma unroll 4
            for (int d = 0; d < DD; d += 4) {
                a0 = fmaf(s_vec[d],     wk[(long)d * DD + t],       a0);
                a1 = fmaf(s_vec[d + 1], wk[(long)(d + 1) * DD + t], a1);
                a2 = fmaf(s_vec[d + 2], wk[(long)(d + 2) * DD + t], a2);
                a3 = fmaf(s_vec[d + 3], wk[(long)(d + 3) * DD + t], a3);
            }
            ws[WS_C + t] = (a0 + a1 + a2 + a3) * inv;
        }
    } else if (blk == 2 * DD + 1) {
        if (t < DD) s_vec[t] = ipb[DD + t];
        __syncthreads();
        if (t < DD) {
            float a0 = 0.f, a1 = 0.f, a2 = 0.f, a3 = 0.f;
            #pragma unroll 4
            for (int d = 0; d < DD; d += 4) {
                a0 = fmaf(s_vec[d],     ipw[(long)d * DD + t],       a0);
                a1 = fmaf(s_vec[d + 1], ipw[(long)(d + 1) * DD + t], a1);
                a2 = fmaf(s_vec[d + 2], ipw[(long)(d + 2) * DD + t], a2);
                a3 = fmaf(s_vec[d + 3], ipw[(long)(d + 3) * DD + t], a3);
            }
            ws[WS_U + t] = (a0 + a1 + a2 + a3) * inv;
        }
    } else {
        if (t < DD) s_vec[t] = ipb[2 * DD + t];
        __syncthreads();
        if (t < DD) {
            const float* owr = ow + (long)t * DD;
            float a0 = 0.f, a1 = 0.f, a2 = 0.f, a3 = 0.f;
            #pragma unroll 4
            for (int d = 0; d < DD; d += 4) {
                a0 = fmaf(s_vec[d],     owr[d],     a0);
                a1 = fmaf(s_vec[d + 1], owr[d + 1], a1);
                a2 = fmaf(s_vec[d + 2], owr[d + 2], a2);
                a3 = fmaf(s_vec[d + 3], owr[d + 3], a3);
            }
            ws[WS_B2 + t] = ob[t] + (a0 + a1 + a2 + a3);
        }
        if (t >= 192) {
            const int lane = t - 192;
            float p = ipb[lane] * ipb[DD + lane];
            p = fmaf(ipb[lane + 64], ipb[DD + lane + 64], p);
            if (lane < 32) p = fmaf(ipb[lane + 128], ipb[DD + lane + 128], p);
            const float s = wave_sum(p);
            if (lane == 0) ws[WS_S0] = s * inv;
        }
    }
}

// ---------------- main ------------------------------------------------------
// 512 threads = 8 waves; rows r = w>>1; k-half h = w&1. Grid 1024.
// Each half-wave: 4 tiles of 8 k's; per tile, 8-lane teams stream a fp32 x-row
// once (score dot on the fly), stage fp16 in LDS, accumulate wkv-half with
// online softmax. Halves merged exactly via (m,l) log-sum-exp.
// Weight gemvs: 4:1-dedup gemv512 (grid & pressure unchanged vs R10).
// 1024 blocks x 8 waves = 32 waves/CU theoretical IF vgpr<=64; LDS ~38KB x4 fits.
__global__ __launch_bounds__(512, 4)
void structure_learner_kernel(
    const float* __restrict__ x,
    const int*   __restrict__ target_node_ids,
    const int*   __restrict__ target_node_times,
    const int*   __restrict__ neighbor_ids,
    const int*   __restrict__ edge_time,
    const float* __restrict__ edge_weight,
    const float* __restrict__ gumbel_u,
    const float* __restrict__ te_w,
    const float* __restrict__ te_b,
    const float* __restrict__ mlp_w,
    const float* __restrict__ mlp_b,
    const float* __restrict__ ws,
    const float* __restrict__ tetab,   // nullptr -> cos in-kernel
    float* __restrict__ out_ao,
    float* __restrict__ out_new,
    float* __restrict__ out_mask)
{
    __shared__ __attribute__((aligned(16))) _Float16 s_xh[ROWS][2][KT][XH_STRIDE];
    __shared__ __attribute__((aligned(16))) float s_qin[ROWS][LD];
    __shared__ __attribute__((aligned(16))) float s_qt[ROWS][LD];
    __shared__ __attribute__((aligned(16))) float s_wkvh[ROWS][2][LD];
    __shared__ __attribute__((aligned(16))) float s_ao[ROWS][LD];
    __shared__ float  s_aw[ROWS][KK];      // e = exp(sc - m_tile) per k
    __shared__ float  s_mt[ROWS][2][4];    // running-max snapshot per half/tile
    __shared__ float2 s_ml[ROWS][2];       // final (m, l) per half
    __shared__ int    s_nid[ROWS][KK];
    __shared__ int    s_et[ROWS][KK];

    const int tid  = threadIdx.x;
    const int w    = tid >> 6;    // 0..7
    const int lane = tid & 63;
    const int wr   = w >> 1;      // row 0..3
    const int h    = w & 1;       // k-half
    const int b    = blockIdx.x * ROWS + wr;

    const float* Mw = ws + WS_M;
    const float* V2 = ws + WS_V2;
    const float* Cv = ws + WS_C;
    const float* Uv = ws + WS_U;
    const float* B2 = ws + WS_B2;
    const float  s0 = ws[WS_S0];

    // ---- P0: meta + q_in (wave-pair splits the loads) ----
    {
        const long eb = (long)b * KK + lane;
        if (h == 0) {
            s_nid[wr][lane] = neighbor_ids[eb];
            const int tn = target_node_ids[b];
            const float2 tx = *(const float2*)(x + (long)tn * F_DIM + lane * 2);
            s_qin[wr][lane * 2]     = tx.x;
            s_qin[wr][lane * 2 + 1] = tx.y;
        } else {
            s_et[wr][lane] = edge_time[eb];
            if (lane < TE_DIM) {
                const int tt = target_node_times[b];
                s_qin[wr][F_DIM + lane] =
                    (tetab && (unsigned)tt < (unsigned)TAB_T)
                        ? tetab[(long)tt * TE_DIM + lane]
                        : cosf(fmaf((float)tt, te_w[lane], te_b[lane]));
            }
        }
    }
    __syncthreads();

    // ---- P1: q_tilde = M @ q_in + c (512 threads, 4:1 dedup) ----
    gemv512(Mw, Cv, s_qin, s_qt, tid);
    __syncthreads();

    // ---- sbk = q_in . U + s0 (redundant per wave; bit-identical) ----
    float p = s_qin[wr][lane] * Uv[lane];
    p = fmaf(s_qin[wr][lane + 64], Uv[lane + 64], p);
    if (lane < 32) p = fmaf(s_qin[wr][128 + lane], Uv[128 + lane], p);
    const float sbk = wave_sum(p) + s0;

    // ---- K-tile loop over own half: 4 tiles of 8; 8-lane teams/row ----
    const int q = lane >> 3;   // team 0..7 = staged row within tile
    const int j = lane & 7;    // feature sixteenth: dims [16j, 16j+16)
    float m_run = -3.0e38f, l_run = 0.f;
    float ax = 0.f, ay = 0.f, at = 0.f;

    for (int ti = 0; ti < 4; ++ti) {
        const int k   = 32 * h + KT * ti + q;
        const int nid = s_nid[wr][k];
        const int et  = s_et[wr][k];

        // stream 16 dims: fp32 score dot + fp16 write-through stage
        const float4* xr  = (const float4*)(x + (long)nid * F_DIM + 16 * j);
        const float4* qt4 = (const float4*)(s_qt[wr] + 16 * j);
        _Float16* st = &s_xh[wr][h][q][16 * j];
        float a0 = 0.f, a1 = 0.f;
        #pragma unroll
        for (int f = 0; f < 4; f += 2) {
            const float4 A = xr[f], B = xr[f + 1];
            a0 = dot4acc(A, qt4[f],     a0);
            a1 = dot4acc(B, qt4[f + 1], a1);
            union { _Float16 hh[4]; unsigned long long u; } pa, pb;
            pa.hh[0] = (_Float16)A.x; pa.hh[1] = (_Float16)A.y;
            pa.hh[2] = (_Float16)A.z; pa.hh[3] = (_Float16)A.w;
            pb.hh[0] = (_Float16)B.x; pb.hh[1] = (_Float16)B.y;
            pb.hh[2] = (_Float16)B.z; pb.hh[3] = (_Float16)B.w;
            *(unsigned long long*)&st[4 * f]     = pa.u;
            *(unsigned long long*)&st[4 * f + 4] = pb.u;
        }
        float acc = a0 + a1;

        // te: 4 dims [4j, 4j+4) — fp32 in score, fp16 into stage
        {
            const float* qte = s_qt[wr] + F_DIM + 4 * j;
            _Float16* stt = &s_xh[wr][h][q][F_DIM + 4 * j];
            if (tetab && (unsigned)et < (unsigned)TAB_T) {
                const float4 T = *(const float4*)(tetab + (long)et * TE_DIM + 4 * j);
                acc = fmaf(T.x, qte[0], acc);
                acc = fmaf(T.y, qte[1], acc);
                acc = fmaf(T.z, qte[2], acc);
                acc = fmaf(T.w, qte[3], acc);
                union { _Float16 hh[4]; unsigned long long u; } pt;
                pt.hh[0] = (_Float16)T.x; pt.hh[1] = (_Float16)T.y;
                pt.hh[2] = (_Float16)T.z; pt.hh[3] = (_Float16)T.w;
                *(unsigned long long*)&stt[0] = pt.u;
            } else {
                const float etv = (float)et;
                #pragma unroll
                for (int ii = 0; ii < 4; ++ii) {
                    const float cte = cosf(fmaf(etv, te_w[4 * j + ii], te_b[4 * j + ii]));
                    acc = fmaf(cte, qte[ii], acc);
                    stt[ii] = (_Float16)cte;
                }
            }
        }

        // 8-lane team reduce -> all 8 lanes hold the full score
        acc += __shfl_xor(acc, 1, 64);
        acc += __shfl_xor(acc, 2, 64);
        acc += __shfl_xor(acc, 4, 64);
        const float sc = acc + sbk;

        // online softmax update (wave-uniform m, l over own half)
        const float mt   = wave_max(sc);
        const float mnew = fmaxf(m_run, mt);
        const float cfac = expf(m_run - mnew);       // 0 on first tile
        const float e    = expf(sc - mnew);
        l_run = l_run * cfac + wave_sum(e) * 0.125f; // each score duplicated 8x (exact)
        m_run = mnew;
        if (j == 0)    s_aw[wr][k]      = e;
        if (lane == 0) s_mt[wr][h][ti]  = mnew;
        __syncthreads();   // stage + e visible (uniform: all 8 waves, 4 tiles)

        // wkv-half accumulate from the LDS stage (lane = feature pair)
        ax *= cfac; ay *= cfac; at *= cfac;
        #pragma unroll
        for (int qq = 0; qq < KT; ++qq) {
            const float wgt = s_aw[wr][32 * h + KT * ti + qq];
            union { unsigned u; _Float16 h2[2]; } cc;
            cc.u = *(const unsigned*)&s_xh[wr][h][qq][2 * lane];
            ax = fmaf(wgt, (float)cc.h2[0], ax);
            ay = fmaf(wgt, (float)cc.h2[1], ay);
            if (lane < TE_DIM) at = fmaf(wgt, (float)s_xh[wr][h][qq][F_DIM + lane], at);
        }
        __syncthreads();   // stage may be overwritten next tile
    }

    // ---- exact half merge: m = max(m0,m1), l = l0 e^{m0-m} + l1 e^{m1-m} ----
    if (lane == 0) s_ml[wr][h] = make_float2(m_run, l_run);
    __syncthreads();
    const float2 M0 = s_ml[wr][0], M1 = s_ml[wr][1];
    const float  mF = fmaxf(M0.x, M1.x);
    const float  lF = M0.y * expf(M0.x - mF) + M1.y * expf(M1.x - mF);
    const float  sch = expf(m_run - mF) / lF;   // own-half scale

    s_wkvh[wr][h][lane * 2]     = ax * sch;
    s_wkvh[wr][h][lane * 2 + 1] = ay * sch;
    if (lane < TE_DIM) s_wkvh[wr][h][F_DIM + lane] = at * sch;

    // prefetch P5 inputs (epilogue wave only; hide under P4)
    float u = 0.f, ew = 0.f;
    if (h == 0) {
        u  = gumbel_u[(long)b * KK + lane];
        ew = edge_weight[(long)b * KK + lane];
    }
    __syncthreads();

    // ---- P4: ao = V2 @ (wkv0 + wkv1) + b2 ----
    gemv512_2(V2, B2, s_wkvh, s_ao, tid);
    __syncthreads();

    // ---- P5: epilogue (h==0 wave per row; lane = k over all 64) ----
    if (h == 0) {
        const int   hk = lane >> 5;
        const int   tk = (lane & 31) >> 3;
        const float aw = s_aw[wr][lane] * expf(s_mt[wr][hk][tk] - mF) / lF;

        float pm = s_ao[wr][lane] * mlp_w[lane];
        pm = fmaf(s_ao[wr][lane + 64], mlp_w[lane + 64], pm);
        if (lane < 32) pm = fmaf(s_ao[wr][lane + 128], mlp_w[lane + 128], pm);
        const float base = wave_sum(pm) + mlp_b[0];

        float* ao = out_ao + (long)b * DD;
        ao[lane]      = s_ao[wr][lane];
        ao[lane + 64] = s_ao[wr][lane + 64];
        if (lane < 32) ao[lane + 128] = s_ao[wr][lane + 128];

        const float g = -logf(-logf(u + 1e-10f) + 1e-10f);
        const float z = aw + g;  // TAU = 1.0
        const float m = wave_max(z);
        const float e = expf(z - m);
        const float l = wave_sum(e);
        out_mask[(long)b * KK + lane] = (e / l > 0.2f) ? 1.0f : 0.0f;

        const float val = fmaf(ew, mlp_w[DD], base);
        out_new[(long)b * KK + lane] = (val >= 0.f) ? val : 0.01f * val;
    }
}

extern "C" void kernel_launch(void* const* d_in, const int* in_sizes, int n_in,
                              void* d_out, int out_size, void* d_ws, size_t ws_size,
                              hipStream_t stream) {
    const float* x   = (const float*)d_in[0];
    const int*   tni = (const int*)d_in[1];
    const int*   tnt = (const int*)d_in[2];
    const int*   nid = (const int*)d_in[3];
    const int*   et  = (const int*)d_in[4];
    const float* ew  = (const float*)d_in[5];
    const float* gu  = (const float*)d_in[6];
    const float* tew = (const float*)d_in[7];
    const float* teb = (const float*)d_in[8];
    const float* ipw = (const float*)d_in[9];
    const float* ipb = (const float*)d_in[10];
    const float* ow  = (const float*)d_in[11];
    const float* ob  = (const float*)d_in[12];
    const float* mw  = (const float*)d_in[13];
    const float* mb  = (const float*)d_in[14];

    float* wsf = (float*)d_ws;

    float* out      = (float*)d_out;
    float* out_ao   = out;
    float* out_new  = out + (long)NB * DD;
    float* out_mask = out + (long)NB * DD + (long)NB * KK;

    const bool use_tab = ws_size >= (size_t)(WS_TE + TAB_N) * sizeof(float);
    const int  setup_grid = SETUP_BASE + (use_tab ? TAB_BLOCKS : 0);

    setup_kernel<<<setup_grid, 256, 0, stream>>>(ipw, ipb, ow, ob, tew, teb, wsf);

    structure_learner_kernel<<<NB / ROWS, 512, 0, stream>>>(
        x, tni, tnt, nid, et, ew, gu, tew, teb, mw, mb, wsf,
        use_tab ? (wsf + WS_TE) : nullptr,
        out_ao, out_new, out_mask);
}

// Round 13
// 161.923 us; speedup vs baseline: 1.0356x; 1.0356x over previous
//
#include <hip/hip_runtime.h>

#define F_DIM 128
#define TE_DIM 32
#define DD 160
#define NB 4096
#define KK 64
#define ROWS 4
#define LD 164         // padded fp32 LDS row stride
#define XH_STRIDE 168  // staged fp16 row stride (84 dwords; 16B-aligned rows)
#define KT 16          // k-tile size (4 tiles)

// ws layout (float offsets)
#define WS_M   0          // [160][160]  (Wk^T Wq) / sqrt(160)
#define WS_V2  25600      // [160][160]  out_w @ Wv
#define WS_C   51200      // [160]       (Wk^T bq) / sqrt(160)
#define WS_U   51360      // [160]       (Wq^T bk) / sqrt(160)
#define WS_B2  51520      // [160]       out_w @ bv + out_b
#define WS_S0  51680      // [1]         (bq . bk) / sqrt(160)
#define WS_TE  51684      // [10000][32] cos(t*te_w[d]+te_b[d])
#define TAB_T  10000
#define TAB_N  (TAB_T * TE_DIM)
#define TAB_BLOCKS 250
#define SETUP_BASE (2 * DD + 3)

__device__ __forceinline__ float dot4acc(const float4 w, const float4 v, float a) {
    a = fmaf(w.x, v.x, a);
    a = fmaf(w.y, v.y, a);
    a = fmaf(w.z, v.z, a);
    a = fmaf(w.w, v.w, a);
    return a;
}

__device__ __forceinline__ float wave_max(float v) {
    #pragma unroll
    for (int off = 32; off > 0; off >>= 1) v = fmaxf(v, __shfl_xor(v, off, 64));
    return v;
}
__device__ __forceinline__ float wave_sum(float v) {
    #pragma unroll
    for (int off = 32; off > 0; off >>= 1) v += __shfl_xor(v, off, 64);
    return v;
}

// Block-cooperative GEMV (R1-proven): r = tid&3, dl = tid>>2.
// Lanes 4t..4t+3 share weight addresses -> 4:1 dedup in the coalescer.
__device__ __forceinline__ void gemv_rows(
    const float* __restrict__ W, const float* __restrict__ bias,
    const float (*vin)[LD], float (*vout)[LD], int tid)
{
    const int r  = tid & 3;
    const int dl = tid >> 2;
    const float4* v4 = (const float4*)vin[r];
    const float4* w0 = (const float4*)(W + (long)dl * DD);
    const float4* w1 = (const float4*)(W + (long)(dl + 64) * DD);
    float a0 = bias[dl];
    float a1 = bias[dl + 64];
    if (dl < 32) {
        const float4* w2 = (const float4*)(W + (long)(dl + 128) * DD);
        float a2 = bias[dl + 128];
        #pragma unroll 8
        for (int f = 0; f < 40; ++f) {
            const float4 v = v4[f];
            a0 = dot4acc(w0[f], v, a0);
            a1 = dot4acc(w1[f], v, a1);
            a2 = dot4acc(w2[f], v, a2);
        }
        vout[r][dl]       = a0;
        vout[r][dl + 64]  = a1;
        vout[r][dl + 128] = a2;
    } else {
        #pragma unroll 8
        for (int f = 0; f < 40; ++f) {
            const float4 v = v4[f];
            a0 = dot4acc(w0[f], v, a0);
            a1 = dot4acc(w1[f], v, a1);
        }
        vout[r][dl]      = a0;
        vout[r][dl + 64] = a1;
    }
}

// ---------------- setup: fold weight matrices + te table -------------------
__global__ __launch_bounds__(256)
void setup_kernel(const float* __restrict__ ipw, const float* __restrict__ ipb,
                  const float* __restrict__ ow,  const float* __restrict__ ob,
                  const float* __restrict__ te_w, const float* __restrict__ te_b,
                  float* __restrict__ ws)
{
    const int blk = blockIdx.x;
    const int t   = threadIdx.x;
    const float inv = 0.07905694150420949f;  // 1/sqrt(160)

    __shared__ float s_vec[DD];

    if (blk >= SETUP_BASE) {
        const int g0 = (blk - SETUP_BASE) * 256 + t;
        #pragma unroll
        for (int it = 0; it < 5; ++it) {
            const int g = g0 + it * (TAB_BLOCKS * 256);
            const int tt = g >> 5, d = g & 31;
            ws[WS_TE + g] = cosf(fmaf((float)tt, te_w[d], te_b[d]));
        }
        return;
    }

    if (blk < DD) {
        const float* wk = ipw + DD * DD;
        if (t < DD) s_vec[t] = wk[(long)t * DD + blk];
        __syncthreads();
        if (t < DD) {
            float a0 = 0.f, a1 = 0.f, a2 = 0.f, a3 = 0.f;
            #pragma unroll 4
            for (int d = 0; d < DD; d += 4) {
                a0 = fmaf(s_vec[d],     ipw[(long)d * DD + t],       a0);
                a1 = fmaf(s_vec[d + 1], ipw[(long)(d + 1) * DD + t], a1);
                a2 = fmaf(s_vec[d + 2], ipw[(long)(d + 2) * DD + t], a2);
                a3 = fmaf(s_vec[d + 3], ipw[(long)(d + 3) * DD + t], a3);
            }
            ws[WS_M + blk * DD + t] = (a0 + a1 + a2 + a3) * inv;
        }
    } else if (blk < 2 * DD) {
        const int i = blk - DD;
        const float* wv = ipw + 2 * DD * DD;
        if (t < DD) s_vec[t] = ow[(long)i * DD + t];
        __syncthreads();
        if (t < DD) {
            float a0 = 0.f, a1 = 0.f, a2 = 0.f, a3 = 0.f;
            #pragma unroll 4
            for (int d = 0; d < DD; d += 4) {
                a0 = fmaf(s_vec[d],     wv[(long)d * DD + t],       a0);
                a1 = fmaf(s_vec[d + 1], wv[(long)(d + 1) * DD + t], a1);
                a2 = fmaf(s_vec[d + 2], wv[(long)(d + 2) * DD + t], a2);
                a3 = fmaf(s_vec[d + 3], wv[(long)(d + 3) * DD + t], a3);
            }
            ws[WS_V2 + i * DD + t] = a0 + a1 + a2 + a3;
        }
    } else if (blk == 2 * DD) {
        const float* wk = ipw + DD * DD;
        if (t < DD) s_vec[t] = ipb[t];
        __syncthreads();
        if (t < DD) {
            float a0 = 0.f, a1 = 0.f, a2 = 0.f, a3 = 0.f;
            #pragma unroll 4
            for (int d = 0; d < DD; d += 4) {
                a0 = fmaf(s_vec[d],     wk[(long)d * DD + t],       a0);
                a1 = fmaf(s_vec[d + 1], wk[(long)(d + 1) * DD + t], a1);
                a2 = fmaf(s_vec[d + 2], wk[(long)(d + 2) * DD + t], a2);
                a3 = fmaf(s_vec[d + 3], wk[(long)(d + 3) * DD + t], a3);
            }
            ws[WS_C + t] = (a0 + a1 + a2 + a3) * inv;
        }
    } else if (blk == 2 * DD + 1) {
        if (t < DD) s_vec[t] = ipb[DD + t];
        __syncthreads();
        if (t < DD) {
            float a0 = 0.f, a1 = 0.f, a2 = 0.f, a3 = 0.f;
            #pragma unroll 4
            for (int d = 0; d < DD; d += 4) {
                a0 = fmaf(s_vec[d],     ipw[(long)d * DD + t],       a0);
                a1 = fmaf(s_vec[d + 1], ipw[(long)(d + 1) * DD + t], a1);
                a2 = fmaf(s_vec[d + 2], ipw[(long)(d + 2) * DD + t], a2);
                a3 = fmaf(s_vec[d + 3], ipw[(long)(d + 3) * DD + t], a3);
            }
            ws[WS_U + t] = (a0 + a1 + a2 + a3) * inv;
        }
    } else {
        if (t < DD) s_vec[t] = ipb[2 * DD + t];
        __syncthreads();
        if (t < DD) {
            const float* owr = ow + (long)t * DD;
            float a0 = 0.f, a1 = 0.f, a2 = 0.f, a3 = 0.f;
            #pragma unroll 4
            for (int d = 0; d < DD; d += 4) {
                a0 = fmaf(s_vec[d],     owr[d],     a0);
                a1 = fmaf(s_vec[d + 1], owr[d + 1], a1);
                a2 = fmaf(s_vec[d + 2], owr[d + 2], a2);
                a3 = fmaf(s_vec[d + 3], owr[d + 3], a3);
            }
            ws[WS_B2 + t] = ob[t] + (a0 + a1 + a2 + a3);
        }
        if (t >= 192) {
            const int lane = t - 192;
            float p = ipb[lane] * ipb[DD + lane];
            p = fmaf(ipb[lane + 64], ipb[DD + lane + 64], p);
            if (lane < 32) p = fmaf(ipb[lane + 128], ipb[DD + lane + 128], p);
            const float s = wave_sum(p);
            if (lane == 0) ws[WS_S0] = s * inv;
        }
    }
}

// ---------------- main ------------------------------------------------------
// Verified-best structure (R10): ROWS=4, 256 threads, wave = row, grid 1024,
// 4:1-dedup gemvs. K in 4 tiles of 16 with online softmax. Per tile, 4-lane
// teams stream a fp32 x-row once (score dot on the fly), stage fp16 in LDS,
// then wkv accumulates from the stage. x touched ONCE from global.
__global__ __launch_bounds__(256, 4)
void structure_learner_kernel(
    const float* __restrict__ x,
    const int*   __restrict__ target_node_ids,
    const int*   __restrict__ target_node_times,
    const int*   __restrict__ neighbor_ids,
    const int*   __restrict__ edge_time,
    const float* __restrict__ edge_weight,
    const float* __restrict__ gumbel_u,
    const float* __restrict__ te_w,
    const float* __restrict__ te_b,
    const float* __restrict__ mlp_w,
    const float* __restrict__ mlp_b,
    const float* __restrict__ ws,
    const float* __restrict__ tetab,   // nullptr -> cos in-kernel
    float* __restrict__ out_ao,
    float* __restrict__ out_new,
    float* __restrict__ out_mask)
{
    __shared__ __attribute__((aligned(16))) _Float16 s_xh[ROWS][KT][XH_STRIDE];
    __shared__ __attribute__((aligned(16))) float s_qin[ROWS][LD];
    __shared__ __attribute__((aligned(16))) float s_qt[ROWS][LD];
    __shared__ __attribute__((aligned(16))) float s_wkv[ROWS][LD];
    __shared__ __attribute__((aligned(16))) float s_ao[ROWS][LD];
    __shared__ float s_aw[ROWS][KK];   // exp(s_k - m_tile) per k
    __shared__ float s_mt[ROWS][4];    // running max snapshot per tile
    __shared__ int   s_nid[ROWS][KK];
    __shared__ int   s_et[ROWS][KK];

    const int tid  = threadIdx.x;
    const int wr   = tid >> 6;   // wave == row
    const int lane = tid & 63;
    const int b    = blockIdx.x * ROWS + wr;

    const float* Mw = ws + WS_M;
    const float* V2 = ws + WS_V2;
    const float* Cv = ws + WS_C;
    const float* Uv = ws + WS_U;
    const float* B2 = ws + WS_B2;
    const float  s0 = ws[WS_S0];

    // ---- P0: meta + q_in ----
    {
        const long eb = (long)b * KK + lane;
        s_nid[wr][lane] = neighbor_ids[eb];
        s_et[wr][lane]  = edge_time[eb];
        const int tn = target_node_ids[b];
        const float2 tx = *(const float2*)(x + (long)tn * F_DIM + lane * 2);
        s_qin[wr][lane * 2]     = tx.x;
        s_qin[wr][lane * 2 + 1] = tx.y;
        if (lane < TE_DIM) {
            const int tt = target_node_times[b];
            s_qin[wr][F_DIM + lane] =
                (tetab && (unsigned)tt < (unsigned)TAB_T)
                    ? tetab[(long)tt * TE_DIM + lane]
                    : cosf(fmaf((float)tt, te_w[lane], te_b[lane]));
        }
    }
    __syncthreads();

    // ---- P1: q_tilde = M @ q_in + c ----
    gemv_rows(Mw, Cv, s_qin, s_qt, tid);
    __syncthreads();

    // ---- sbk = q_in . U + s0 (wave-uniform) ----
    float p = s_qin[wr][lane] * Uv[lane];
    p = fmaf(s_qin[wr][lane + 64], Uv[lane + 64], p);
    if (lane < 32) p = fmaf(s_qin[wr][128 + lane], Uv[128 + lane], p);
    const float sbk = wave_sum(p) + s0;

    // ---- K-tile loop: stream-score-stage (fp32 dot, fp16 stage), online SM ----
    const int q = lane >> 2;   // team 0..15 = staged row
    const int j = lane & 3;    // feature quarter
    float m_run = -3.0e38f, l_run = 0.f;
    float ax = 0.f, ay = 0.f, at = 0.f;

    for (int t = 0; t < 4; ++t) {
        const int k   = KT * t + q;
        const int nid = s_nid[wr][k];
        const int et  = s_et[wr][k];

        // stream x quarter: fp32 score dot + fp16 write-through stage
        const float4* xr  = (const float4*)(x + (long)nid * F_DIM + 32 * j);
        const float4* qt4 = (const float4*)(s_qt[wr] + 32 * j);
        _Float16* st = &s_xh[wr][q][32 * j];
        float a0 = 0.f, a1 = 0.f;
        #pragma unroll
        for (int f = 0; f < 8; f += 2) {
            const float4 A = xr[f], B = xr[f + 1];
            a0 = dot4acc(A, qt4[f],     a0);
            a1 = dot4acc(B, qt4[f + 1], a1);
            union { _Float16 hh[4]; unsigned long long u; } pa, pb;
            pa.hh[0] = (_Float16)A.x; pa.hh[1] = (_Float16)A.y;
            pa.hh[2] = (_Float16)A.z; pa.hh[3] = (_Float16)A.w;
            pb.hh[0] = (_Float16)B.x; pb.hh[1] = (_Float16)B.y;
            pb.hh[2] = (_Float16)B.z; pb.hh[3] = (_Float16)B.w;
            *(unsigned long long*)&st[4 * f]     = pa.u;
            *(unsigned long long*)&st[4 * f + 4] = pb.u;
        }
        float acc = a0 + a1;

        // te: 8 dims [8j, 8j+8) — fp32 in score, fp16 into stage
        {
            const float* qte = s_qt[wr] + F_DIM + 8 * j;
            _Float16* stt = &s_xh[wr][q][F_DIM + 8 * j];
            if (tetab && (unsigned)et < (unsigned)TAB_T) {
                const float4* tr = (const float4*)(tetab + (long)et * TE_DIM + 8 * j);
                const float4 T0 = tr[0], T1 = tr[1];
                acc = fmaf(T0.x, qte[0], acc);
                acc = fmaf(T0.y, qte[1], acc);
                acc = fmaf(T0.z, qte[2], acc);
                acc = fmaf(T0.w, qte[3], acc);
                acc = fmaf(T1.x, qte[4], acc);
                acc = fmaf(T1.y, qte[5], acc);
                acc = fmaf(T1.z, qte[6], acc);
                acc = fmaf(T1.w, qte[7], acc);
                union { _Float16 hh[4]; unsigned long long u; } p0, p1;
                p0.hh[0] = (_Float16)T0.x; p0.hh[1] = (_Float16)T0.y;
                p0.hh[2] = (_Float16)T0.z; p0.hh[3] = (_Float16)T0.w;
                p1.hh[0] = (_Float16)T1.x; p1.hh[1] = (_Float16)T1.y;
                p1.hh[2] = (_Float16)T1.z; p1.hh[3] = (_Float16)T1.w;
                *(unsigned long long*)&stt[0] = p0.u;
                *(unsigned long long*)&stt[4] = p1.u;
            } else {
                const float etv = (float)et;
                #pragma unroll
                for (int ii = 0; ii < 8; ++ii) {
                    const float cte = cosf(fmaf(etv, te_w[8 * j + ii], te_b[8 * j + ii]));
                    acc = fmaf(cte, qte[ii], acc);
                    stt[ii] = (_Float16)cte;
                }
            }
        }

        // 4-lane team reduce -> all 4 lanes hold the full score (bit-identical)
        acc += __shfl_xor(acc, 1, 64);
        acc += __shfl_xor(acc, 2, 64);
        const float sc = acc + sbk;

        // online softmax update (wave-uniform m, l)
        const float mt   = wave_max(sc);
        const float mnew = fmaxf(m_run, mt);
        const float cfac = expf(m_run - mnew);   // 0 on first tile
        const float e    = expf(sc - mnew);
        l_run = l_run * cfac + wave_sum(e) * 0.25f;  // each score duplicated 4x (exact)
        m_run = mnew;
        if (j == 0)    s_aw[wr][k]  = e;
        if (lane == 0) s_mt[wr][t]  = mnew;
        __syncthreads();   // stage + e visible (uniform across all 4 waves)

        // wkv accumulate from the LDS stage (lane = feature pair)
        ax *= cfac; ay *= cfac; at *= cfac;
        #pragma unroll
        for (int qq = 0; qq < KT; ++qq) {
            const float wgt = s_aw[wr][KT * t + qq];
            union { unsigned u; _Float16 h2[2]; } cc;
            cc.u = *(const unsigned*)&s_xh[wr][qq][2 * lane];
            ax = fmaf(wgt, (float)cc.h2[0], ax);
            ay = fmaf(wgt, (float)cc.h2[1], ay);
            if (lane < TE_DIM) at = fmaf(wgt, (float)s_xh[wr][qq][F_DIM + lane], at);
        }
        __syncthreads();   // stage may be overwritten next tile
    }

    // ---- finalize wkv = (sum e_k x_k) / l ----
    const float rl = 1.f / l_run;
    s_wkv[wr][lane * 2]     = ax * rl;
    s_wkv[wr][lane * 2 + 1] = ay * rl;
    if (lane < TE_DIM) s_wkv[wr][F_DIM + lane] = at * rl;

    // prefetch P5 inputs (hide under P4)
    const float u  = gumbel_u[(long)b * KK + lane];
    const float ew = edge_weight[(long)b * KK + lane];
    __syncthreads();

    // ---- P4: ao = V2 @ wkv + b2 ----
    gemv_rows(V2, B2, s_wkv, s_ao, tid);
    __syncthreads();

    // ---- P5: epilogue (wave per row, lane = k) ----
    {
        const float awk = s_aw[wr][lane] * expf(s_mt[wr][lane >> 4] - m_run) * rl;

        float pm = s_ao[wr][lane] * mlp_w[lane];
        pm = fmaf(s_ao[wr][lane + 64], mlp_w[lane + 64], pm);
        if (lane < 32) pm = fmaf(s_ao[wr][lane + 128], mlp_w[lane + 128], pm);
        const float base = wave_sum(pm) + mlp_b[0];

        float* ao = out_ao + (long)b * DD;
        ao[lane]      = s_ao[wr][lane];
        ao[lane + 64] = s_ao[wr][lane + 64];
        if (lane < 32) ao[lane + 128] = s_ao[wr][lane + 128];

        const float g = -logf(-logf(u + 1e-10f) + 1e-10f);
        const float z = awk + g;  // TAU = 1.0
        const float m = wave_max(z);
        const float e = expf(z - m);
        const float l = wave_sum(e);
        out_mask[(long)b * KK + lane] = (e / l > 0.2f) ? 1.0f : 0.0f;

        const float val = fmaf(ew, mlp_w[DD], base);
        out_new[(long)b * KK + lane] = (val >= 0.f) ? val : 0.01f * val;
    }
}

extern "C" void kernel_launch(void* const* d_in, const int* in_sizes, int n_in,
                              void* d_out, int out_size, void* d_ws, size_t ws_size,
                              hipStream_t stream) {
    const float* x   = (const float*)d_in[0];
    const int*   tni = (const int*)d_in[1];
    const int*   tnt = (const int*)d_in[2];
    const int*   nid = (const int*)d_in[3];
    const int*   et  = (const int*)d_in[4];
    const float* ew  = (const float*)d_in[5];
    const float* gu  = (const float*)d_in[6];
    const float* tew = (const float*)d_in[7];
    const float* teb = (const float*)d_in[8];
    const float* ipw = (const float*)d_in[9];
    const float* ipb = (const float*)d_in[10];
    const float* ow  = (const float*)d_in[11];
    const float* ob  = (const float*)d_in[12];
    const float* mw  = (const float*)d_in[13];
    const float* mb  = (const float*)d_in[14];

    float* wsf = (float*)d_ws;

    float* out      = (float*)d_out;
    float* out_ao   = out;
    float* out_new  = out + (long)NB * DD;
    float* out_mask = out + (long)NB * DD + (long)NB * KK;

    const bool use_tab = ws_size >= (size_t)(WS_TE + TAB_N) * sizeof(float);
    const int  setup_grid = SETUP_BASE + (use_tab ? TAB_BLOCKS : 0);

    setup_kernel<<<setup_grid, 256, 0, stream>>>(ipw, ipb, ow, ob, tew, teb, wsf);

    structure_learner_kernel<<<NB / ROWS, 256, 0, stream>>>(
        x, tni, tnt, nid, et, ew, gu, tew, teb, mw, mb, wsf,
        use_tab ? (wsf + WS_TE) : nullptr,
        out_ao, out_new, out_mask);
}